// Round 13
// baseline (345.292 us; speedup 1.0000x reference)
//
#include <hip/hip_runtime.h>
#include <math.h>

#define N_NODES 100000
#define NFEAT 256
#define D1 64          // HEADS*NHID
#define HEADS 8
#define NHID 8
#define NCLASS 32
#define NUM_EDGES 1600000
#define E_TOT 1700000  // + self loops
#define NEG_SLOPE 0.2f
#define SENT N_NODES   // sentinel node: als=-inf (w=0), zero feature row

// dst-bucketing: 256 nodes per bucket
#define BSHIFT 8
#define NBUCK 391            // ceil(100000/256)
#define BCAP_BIN 5120        // unpadded: mean 4352, +11.6 sigma
#define BCAP_CSR 8192        // padded-to-16: mean ~6272, +15 sigma
#define BIN_EPB 4096
#define BIN_EPT 16
#define GEMM1_NB 1563        // ceil(100000/64)

// LESSON (r4): wave-per-node x 25k waves >> block-per-bucket (TLP hides gather latency).
// LESSON (r9/r14): gather MLP (8 edge slots x uint4 + 2-deep pipeline) 76->63us.
// LESSON (r10-r13): gemm1 pipelining only sticks with __syncthreads between issue and use.
// LESSON (r16-r21): fused layer2/logsoftmax into gathers; fast_elu (not expm1f);
// barrier-FREE wave-local epilogue (zbuf per-wave + wave_barrier): 96->74us.
// LESSON (r22): role-split block fusion {bsort | gemm1} hides bsort under gemm1 (-8us).
// LESSON (r23): gather loops ran only 2-3 iterations (deg~17) and spent issue slots on
// 3 divergent guards/iter. FIX: sentinel-pad CSR segments to multiple of 16 (sentinel
// node N_NODES: als=-inf -> w=0, zero rows) -> branch-free loops, one clamp per iter.
// bsort drops LDS staging (direct scatter, L2-local) -> merged-kernel LDS 23.5->10.25KB.

// ---- workspace layout (float offsets); h1/h2 are PACKED BF16 (uint = 2 ch) ----
// all regions sized for N_NODES+1 (sentinel row)
#define OFF_H1    0            // h1b: 100001*32 uints = 1,600,016 f
#define OFF_H2    6400000      // h2b: 100001*16 uints = 800,008 f
#define OFF_ALS1  12800000     // 800,008 f
#define OFF_ALD1  13700000     // 800,000 f
#define OFF_ALS2  14600000     // 100,001 f
#define OFF_ALD2  14800000     // 100,000 f
#define OFF_BCUR  15000000     // 1024
#define OFF_ROWP  15001024     // 100,000
#define OFF_CNT   15101024     // 100,000
#define OFF_BIN   15201024     // 391*5120 ints
#define OFF_CSR   17202944     // 391*8192 ints (ends 20.4M f = 82MB)

typedef __attribute__((ext_vector_type(8))) short bf16x8;
typedef __attribute__((ext_vector_type(4))) float f32x4;

__device__ __forceinline__ float lrelu(float x) { return x >= 0.f ? x : NEG_SLOPE * x; }
__device__ __forceinline__ float fast_elu(float x) { return x > 0.f ? x : __expf(x) - 1.f; }

__device__ __forceinline__ unsigned f32_to_bf16_rne(float f) {
    unsigned u = __float_as_uint(f);
    return (u + 0x7fffu + ((u >> 16) & 1u)) >> 16;
}
__device__ __forceinline__ unsigned pack_bf16x2(float lo, float hi) {
    return f32_to_bf16_rne(lo) | (f32_to_bf16_rne(hi) << 16);
}
__device__ __forceinline__ float2 unpack_bf16x2(unsigned v) {
    return make_float2(__uint_as_float(v << 16), __uint_as_float(v & 0xffff0000u));
}

__device__ __forceinline__ void edge_src_dst(const int* __restrict__ ei, int e, int& src, int& dst) {
    if (e < NUM_EDGES) { src = ei[e]; dst = ei[NUM_EDGES + e]; }
    else { src = e - NUM_EDGES; dst = e - NUM_EDGES; }
}

// ---------------- K2: bin edges by dst bucket (LDS hist + chunk reservation) ----------------
// packed entry: (dst&255)<<20 | src   (src < 2^17)
__global__ __launch_bounds__(256) void bin_kernel(const int* __restrict__ ei,
                                                  int* __restrict__ bcur,
                                                  int* __restrict__ bin) {
    __shared__ int lcnt[NBUCK];
    __shared__ int lbase[NBUCK];
    const int tid = threadIdx.x;
    for (int b = tid; b < NBUCK; b += 256) lcnt[b] = 0;
    __syncthreads();
    const int e0 = blockIdx.x * BIN_EPB;
    int pk[BIN_EPT], bk[BIN_EPT], loff[BIN_EPT];
#pragma unroll
    for (int i = 0; i < BIN_EPT; i++) {
        const int e = e0 + i * 256 + tid;
        if (e < E_TOT) {
            int src, dst; edge_src_dst(ei, e, src, dst);
            bk[i] = dst >> BSHIFT;
            pk[i] = ((dst & 255) << 20) | src;
            loff[i] = atomicAdd(&lcnt[bk[i]], 1);
        } else bk[i] = -1;
    }
    __syncthreads();
    for (int b = tid; b < NBUCK; b += 256) {
        const int c = lcnt[b];
        lbase[b] = c ? atomicAdd(&bcur[b], c) : 0;
    }
    __syncthreads();
#pragma unroll
    for (int i = 0; i < BIN_EPT; i++) {
        if (bk[i] >= 0)
            bin[(size_t)bk[i] * BCAP_BIN + lbase[bk[i]] + loff[i]] = pk[i];
    }
}

// ---------------- K1+K3 merged: role-split blocks -------------------------------------
// blocks [0, NBUCK): bsort (counting sort -> sentinel-padded CSR, direct global scatter)
// blocks [NBUCK, NBUCK+1563): gemm1 MFMA + fused logit dots (+ sentinel row init)
// LDS union: 10240 B (gemm1 xbf; bsort hists use 3072 of it).
__global__ __launch_bounds__(256) void gemm1_bsort_kernel(const float* __restrict__ x,
                                                          const float* __restrict__ W1,
                                                          const float* __restrict__ a_src,
                                                          const float* __restrict__ a_dst,
                                                          ushort* __restrict__ h1u,
                                                          float* __restrict__ als,
                                                          float* __restrict__ ald,
                                                          const int* __restrict__ bcur,
                                                          const int* __restrict__ bin,
                                                          int* __restrict__ csr,
                                                          int* __restrict__ row_ptr,
                                                          int* __restrict__ cnt) {
    __shared__ __align__(16) unsigned char smem[10240];
    const int tid = threadIdx.x;

    if (blockIdx.x < NBUCK) {
        // ---- bsort role: counting sort with sentinel padding to multiple of 16 ----
        int* hcnt = (int*)smem;          // 256
        int* hpre = hcnt + 256;          // 256
        int* curp = hpre + 256;          // 256
        const int bkt = blockIdx.x;
        const int cntb = bcur[bkt];
        const int base5 = bkt * BCAP_BIN;
        const int base8 = bkt * BCAP_CSR;
        hcnt[tid] = 0;
        __syncthreads();
        for (int i = tid; i < cntb; i += 256)
            atomicAdd(&hcnt[bin[base5 + i] >> 20], 1);
        __syncthreads();
        const int myc = hcnt[tid];
        const int rc = (myc + 15) & ~15;     // padded count (0 stays 0)
        hpre[tid] = rc;
        __syncthreads();
        for (int off = 1; off < 256; off <<= 1) {
            const int t = (tid >= off) ? hpre[tid - off] : 0;
            __syncthreads();
            hpre[tid] += t;
            __syncthreads();
        }
        const int exc = hpre[tid] - rc;
        curp[tid] = exc;
        __syncthreads();
        for (int i = tid; i < cntb; i += 256) {
            const int v = bin[base5 + i];
            const int pos = atomicAdd(&curp[v >> 20], 1);
            csr[base8 + pos] = v & 0xFFFFF;   // direct scatter: 32KB window, L2-local
        }
        // sentinel padding (disjoint from scatter range; no sync needed)
        for (int j = exc + myc; j < exc + rc; j++) csr[base8 + j] = SENT;
        const int n = (bkt << BSHIFT) + tid;
        if (n < N_NODES) { row_ptr[n] = base8 + exc; cnt[n] = rc; }
        return;
    }

    // ---- gemm1 role ----
    unsigned* xbf = (unsigned*)smem;     // [2][64*20] uints (10240 B)
    const int wv = tid >> 6;             // wave = col-tile
    const int l = tid & 63;
    const int lm = l & 15;
    const int quad = l >> 4;
    const int r0 = (blockIdx.x - NBUCK) * 64;

    // sentinel row init (one block): zero h1 row + als1 = -inf
    if (r0 == 0) {
        if (tid < 32) ((unsigned*)h1u)[(size_t)SENT * 32 + tid] = 0u;
        else if (tid < 40) als[(size_t)SENT * HEADS + (tid - 32)] = -INFINITY;
    }

    // B-fragments: this wave's 16-col slice of W1, all 8 K-chunks, in registers (32 VGPRs)
    bf16x8 bfrag[8];
#pragma unroll
    for (int kb = 0; kb < 8; kb++)
#pragma unroll
        for (int j = 0; j < 8; j++) {
            const int k = kb * 32 + quad * 8 + j;
            bfrag[kb][j] = (short)f32_to_bf16_rne(W1[k * D1 + wv * 16 + lm]);
        }

    f32x4 acc[4];
#pragma unroll
    for (int s = 0; s < 4; s++) acc[s] = (f32x4)(0.f);

    const int sr = tid >> 2;            // staging: row 0..63
    const int sk = (tid & 3) * 8;       // k-offset within 32-chunk
    const bool rok = (r0 + sr) < N_NODES;
    const float* xrow = &x[(size_t)(r0 + sr) * NFEAT];
    const int swrd = sr * 20 + (tid & 3) * 4;   // LDS write word offset

    // prologue: load + pack + write chunk 0 into buf 0
    {
        uint4 pv = make_uint4(0, 0, 0, 0);
        if (rok) {
            const float4 va = *(const float4*)&xrow[sk];
            const float4 vb = *(const float4*)&xrow[sk + 4];
            pv.x = pack_bf16x2(va.x, va.y);
            pv.y = pack_bf16x2(va.z, va.w);
            pv.z = pack_bf16x2(vb.x, vb.y);
            pv.w = pack_bf16x2(vb.z, vb.w);
        }
        *(uint4*)&xbf[swrd] = pv;
    }
    __syncthreads();

#pragma unroll
    for (int kb = 0; kb < 8; kb++) {
        const int cur = kb & 1;
        const int nxt = cur ^ 1;
        float4 na = make_float4(0.f, 0.f, 0.f, 0.f);
        float4 nb = make_float4(0.f, 0.f, 0.f, 0.f);
        if (kb < 7 && rok) {
            na = *(const float4*)&xrow[(kb + 1) * 32 + sk];
            nb = *(const float4*)&xrow[(kb + 1) * 32 + sk + 4];
        }
#pragma unroll
        for (int s = 0; s < 4; s++) {
            const uint4 u = *(const uint4*)&xbf[cur * 1280 + (s * 16 + lm) * 20 + quad * 4];
            const bf16x8 af = *(const bf16x8*)&u;
            acc[s] = __builtin_amdgcn_mfma_f32_16x16x32_bf16(af, bfrag[kb], acc[s], 0, 0, 0);
        }
        if (kb < 7) {
            uint4 pv;
            pv.x = pack_bf16x2(na.x, na.y);
            pv.y = pack_bf16x2(na.z, na.w);
            pv.z = pack_bf16x2(nb.x, nb.y);
            pv.w = pack_bf16x2(nb.z, nb.w);
            *(uint4*)&xbf[nxt * 1280 + swrd] = pv;
            __syncthreads();
        }
    }

    // epilogue: bf16 h1 stores + f32 logit dots (shfl over 8-lane head groups)
    const int head = wv * 2 + (lm >> 3);
    const int jc = l & 7;
    const float asl = a_src[head * NHID + jc];
    const float adl = a_dst[head * NHID + jc];
    const int col = wv * 16 + lm;
#pragma unroll
    for (int s = 0; s < 4; s++) {
#pragma unroll
        for (int r = 0; r < 4; r++) {
            const int row = r0 + s * 16 + quad * 4 + r;
            const float v = acc[s][r];
            float ps = v * asl, pd = v * adl;
            ps += __shfl_xor(ps, 1, 64); pd += __shfl_xor(pd, 1, 64);
            ps += __shfl_xor(ps, 2, 64); pd += __shfl_xor(pd, 2, 64);
            ps += __shfl_xor(ps, 4, 64); pd += __shfl_xor(pd, 4, 64);
            if (row < N_NODES) {
                h1u[(size_t)row * D1 + col] = (ushort)f32_to_bf16_rne(v);
                if (jc == 0) { als[row * HEADS + head] = ps; ald[row * HEADS + head] = pd; }
            }
        }
    }
}

// ---------------- K4: gather layer 1 + FUSED layer2 (branch-free loop) ----------------
// Wave/node, 8 lanes x uint4 (head octet), 8 edge slots. Sentinel padding (cnt multiple
// of 16, >=16) makes every load unconditional; one clamp per iteration on the prefetch
// index (clamped loads are never consumed). Epilogue wave-local, barrier-free (r21).
__global__ __launch_bounds__(256) void gather1_kernel(const int* __restrict__ row_ptr,
                                                      const int* __restrict__ cnt,
                                                      const int* __restrict__ csr_src,
                                                      const unsigned* __restrict__ h1b,
                                                      const float* __restrict__ als,
                                                      const float* __restrict__ ald,
                                                      const float* __restrict__ b1,
                                                      const float* __restrict__ W2,
                                                      const float* __restrict__ a_src2,
                                                      const float* __restrict__ a_dst2,
                                                      unsigned* __restrict__ h2b,
                                                      float* __restrict__ als2,
                                                      float* __restrict__ ald2) {
    __shared__ float zbuf[4][64];                // per-wave z row (1 KB)
    const int tid = threadIdx.x;
    const int wv = tid >> 6;
    const int n = blockIdx.x * 4 + wv;           // grid == N_NODES/4 exactly
    const int l = tid & 63;
    const int q = l >> 3;                        // edge slot 0..7
    const int h = l & 7;                         // head = channel octet 8h..8h+7

    // layer-2 sentinel init (any one block; done before gather2 launches)
    if (blockIdx.x == 0 && wv == 0) {
        if (l < 16) h2b[(size_t)SENT * 16 + l] = 0u;
        else if (l == 16) als2[SENT] = -INFINITY;
    }

    const int start = row_ptr[n];
    const int dpad = cnt[n];                     // multiple of 16, >= 16
    const float aldn = ald[n * HEADS + h];
    float a0 = 0.f, a1 = 0.f, a2 = 0.f, a3 = 0.f;
    float a4 = 0.f, a5 = 0.f, a6 = 0.f, a7 = 0.f, wsum = 0.f;

    int i = q;
    // i and i+8 always < 16 <= dpad: unconditional
    const int sA0 = csr_src[start + i];
    const int sB0 = csr_src[start + i + 8];
    int o2 = i + 16; o2 = (o2 < dpad) ? o2 : q;
    int sC = csr_src[start + o2];
    float eA = als[sA0 * HEADS + h];
    uint4 uA = *(const uint4*)&h1b[(size_t)sA0 * 32 + h * 4];
    float eB = als[sB0 * HEADS + h];
    uint4 uB = *(const uint4*)&h1b[(size_t)sB0 * 32 + h * 4];

    for (; i < dpad; i += 8) {
        int o3 = i + 24; o3 = (o3 < dpad) ? o3 : q;
        const int sD = csr_src[start + o3];
        const float eC = als[sC * HEADS + h];
        const uint4 uC = *(const uint4*)&h1b[(size_t)sC * 32 + h * 4];
        const float w = __expf(lrelu(eA + aldn));
        const float2 p0 = unpack_bf16x2(uA.x);
        const float2 p1 = unpack_bf16x2(uA.y);
        const float2 p2 = unpack_bf16x2(uA.z);
        const float2 p3 = unpack_bf16x2(uA.w);
        a0 = fmaf(p0.x, w, a0); a1 = fmaf(p0.y, w, a1);
        a2 = fmaf(p1.x, w, a2); a3 = fmaf(p1.y, w, a3);
        a4 = fmaf(p2.x, w, a4); a5 = fmaf(p2.y, w, a5);
        a6 = fmaf(p3.x, w, a6); a7 = fmaf(p3.y, w, a7);
        wsum += w;
        eA = eB; uA = uB; eB = eC; uB = uC; sC = sD;
    }

    // reduce across the 8 slots (8-lane groups)
    a0 += __shfl_down(a0, 32, 64); a1 += __shfl_down(a1, 32, 64);
    a2 += __shfl_down(a2, 32, 64); a3 += __shfl_down(a3, 32, 64);
    a4 += __shfl_down(a4, 32, 64); a5 += __shfl_down(a5, 32, 64);
    a6 += __shfl_down(a6, 32, 64); a7 += __shfl_down(a7, 32, 64);
    wsum += __shfl_down(wsum, 32, 64);
    a0 += __shfl_down(a0, 16, 64); a1 += __shfl_down(a1, 16, 64);
    a2 += __shfl_down(a2, 16, 64); a3 += __shfl_down(a3, 16, 64);
    a4 += __shfl_down(a4, 16, 64); a5 += __shfl_down(a5, 16, 64);
    a6 += __shfl_down(a6, 16, 64); a7 += __shfl_down(a7, 16, 64);
    wsum += __shfl_down(wsum, 16, 64);
    a0 += __shfl_down(a0, 8, 64); a1 += __shfl_down(a1, 8, 64);
    a2 += __shfl_down(a2, 8, 64); a3 += __shfl_down(a3, 8, 64);
    a4 += __shfl_down(a4, 8, 64); a5 += __shfl_down(a5, 8, 64);
    a6 += __shfl_down(a6, 8, 64); a7 += __shfl_down(a7, 8, 64);
    wsum += __shfl_down(wsum, 8, 64);

    // ---- fused layer2 (wave-local; fast_elu = single v_exp, r17 lesson) ----
    if (l < 8) {                                  // lane l holds channels 8l..8l+7
        const float inv = 1.f / (wsum + 1e-16f);
        const float4 b1a = *(const float4*)&b1[l * 8];
        const float4 b1b = *(const float4*)&b1[l * 8 + 4];
        const float z0 = fast_elu(a0 * inv + b1a.x);
        const float z1 = fast_elu(a1 * inv + b1a.y);
        const float z2 = fast_elu(a2 * inv + b1a.z);
        const float z3 = fast_elu(a3 * inv + b1a.w);
        const float z4 = fast_elu(a4 * inv + b1b.x);
        const float z5 = fast_elu(a5 * inv + b1b.y);
        const float z6 = fast_elu(a6 * inv + b1b.z);
        const float z7 = fast_elu(a7 * inv + b1b.w);
        *(float4*)&zbuf[wv][l * 8]     = make_float4(z0, z1, z2, z3);
        *(float4*)&zbuf[wv][l * 8 + 4] = make_float4(z4, z5, z6, z7);
    }
    __builtin_amdgcn_wave_barrier();             // pin DS write<->read program order
    asm volatile("" ::: "memory");               // forbid compiler value-forwarding

    // y[c] = sum_k z[k] * W2[k][c]; W2 direct from global (L1/L2-hot, r9-verified),
    // 4 partial accumulators to break the serial fmaf chain.
    const int c = l & 31;                         // output class
    const int kh = l >> 5;                        // k-half
    float y0 = 0.f, y1 = 0.f, y2 = 0.f, y3 = 0.f;
    const float* wbase = &W2[(kh * 32) * NCLASS + c];
#pragma unroll
    for (int j4 = 0; j4 < 2; j4++) {
        const int k0 = j4 * 16;
        const float4 za = *(const float4*)&zbuf[wv][kh * 32 + k0];
        const float4 zb = *(const float4*)&zbuf[wv][kh * 32 + k0 + 4];
        const float4 zc = *(const float4*)&zbuf[wv][kh * 32 + k0 + 8];
        const float4 zd = *(const float4*)&zbuf[wv][kh * 32 + k0 + 12];
        y0 = fmaf(za.x, wbase[(k0 + 0) * NCLASS], y0);
        y1 = fmaf(za.y, wbase[(k0 + 1) * NCLASS], y1);
        y2 = fmaf(za.z, wbase[(k0 + 2) * NCLASS], y2);
        y3 = fmaf(za.w, wbase[(k0 + 3) * NCLASS], y3);
        y0 = fmaf(zb.x, wbase[(k0 + 4) * NCLASS], y0);
        y1 = fmaf(zb.y, wbase[(k0 + 5) * NCLASS], y1);
        y2 = fmaf(zb.z, wbase[(k0 + 6) * NCLASS], y2);
        y3 = fmaf(zb.w, wbase[(k0 + 7) * NCLASS], y3);
        y0 = fmaf(zc.x, wbase[(k0 + 8) * NCLASS], y0);
        y1 = fmaf(zc.y, wbase[(k0 + 9) * NCLASS], y1);
        y2 = fmaf(zc.z, wbase[(k0 + 10) * NCLASS], y2);
        y3 = fmaf(zc.w, wbase[(k0 + 11) * NCLASS], y3);
        y0 = fmaf(zd.x, wbase[(k0 + 12) * NCLASS], y0);
        y1 = fmaf(zd.y, wbase[(k0 + 13) * NCLASS], y1);
        y2 = fmaf(zd.z, wbase[(k0 + 14) * NCLASS], y2);
        y3 = fmaf(zd.w, wbase[(k0 + 15) * NCLASS], y3);
    }
    float y = (y0 + y1) + (y2 + y3);
    y += __shfl_xor(y, 32, 64);                   // full y[c] on all lanes

    // layer-2 logit dots: lower half reduces y*a_src2, upper half y*a_dst2
    float part = y * ((l < 32) ? a_src2[c] : a_dst2[c]);
    part += __shfl_xor(part, 1, 64);
    part += __shfl_xor(part, 2, 64);
    part += __shfl_xor(part, 4, 64);
    part += __shfl_xor(part, 8, 64);
    part += __shfl_xor(part, 16, 64);
    const float tdv = __shfl(part, 32, 64);       // td (upper-half sum)
    if (l == 0) { als2[n] = part; ald2[n] = tdv; }

    // pack h2 bf16: even lanes of lower half pack (y[c], y[c+1]) -> word c>>1
    const unsigned pw = pack_bf16x2(y, __shfl_down(y, 1, 64));
    if (l < 32 && (l & 1) == 0) h2b[(size_t)n * 16 + (l >> 1)] = pw;
}

// ---------------- K5: gather layer 2 + FUSED log_softmax (branch-free loop) ----------------
// Wave/node, 4 lanes x uint4 (8ch), 16 edge slots; sentinel-padded counts (mult of 16).
__global__ __launch_bounds__(256) void gather2_kernel(const int* __restrict__ row_ptr,
                                                      const int* __restrict__ cnt,
                                                      const int* __restrict__ csr_src,
                                                      const unsigned* __restrict__ h2b,
                                                      const float* __restrict__ als2,
                                                      const float* __restrict__ ald2,
                                                      const float* __restrict__ b2,
                                                      float* __restrict__ out) {
    const int tid = threadIdx.x;
    const int n = blockIdx.x * 4 + (tid >> 6);   // grid == N_NODES/4 exactly
    const int l = tid & 63;
    const int q = l >> 2;                        // edge slot 0..15
    const int c = l & 3;                         // channel octet: ch 8c..8c+7
    const int start = row_ptr[n];
    const int dpad = cnt[n];                     // multiple of 16, >= 16
    const float aldn = ald2[n];
    float a0 = 0.f, a1 = 0.f, a2 = 0.f, a3 = 0.f;
    float a4 = 0.f, a5 = 0.f, a6 = 0.f, a7 = 0.f, wsum = 0.f;

    int i = q;
    const int sA0 = csr_src[start + i];          // i < 16 <= dpad: unconditional
    int o1 = i + 16; o1 = (o1 < dpad) ? o1 : q;
    int sC = csr_src[start + o1];
    float eA = als2[sA0];
    uint4 uA = *(const uint4*)&h2b[(size_t)sA0 * 16 + c * 4];
    float eB = als2[sC];
    uint4 uB = *(const uint4*)&h2b[(size_t)sC * 16 + c * 4];
    int o2 = i + 32; o2 = (o2 < dpad) ? o2 : q;
    sC = csr_src[start + o2];

    for (; i < dpad; i += 16) {
        int o3 = i + 48; o3 = (o3 < dpad) ? o3 : q;
        const int sD = csr_src[start + o3];
        const float eC = als2[sC];
        const uint4 uC = *(const uint4*)&h2b[(size_t)sC * 16 + c * 4];
        const float w = __expf(lrelu(eA + aldn));
        const float2 p0 = unpack_bf16x2(uA.x);
        const float2 p1 = unpack_bf16x2(uA.y);
        const float2 p2 = unpack_bf16x2(uA.z);
        const float2 p3 = unpack_bf16x2(uA.w);
        a0 = fmaf(p0.x, w, a0); a1 = fmaf(p0.y, w, a1);
        a2 = fmaf(p1.x, w, a2); a3 = fmaf(p1.y, w, a3);
        a4 = fmaf(p2.x, w, a4); a5 = fmaf(p2.y, w, a5);
        a6 = fmaf(p3.x, w, a6); a7 = fmaf(p3.y, w, a7);
        wsum += w;
        eA = eB; uA = uB; eB = eC; uB = uC; sC = sD;
    }

    // reduce across the 16 slots (4-lane groups)
    a0 += __shfl_down(a0, 32, 64); a1 += __shfl_down(a1, 32, 64);
    a2 += __shfl_down(a2, 32, 64); a3 += __shfl_down(a3, 32, 64);
    a4 += __shfl_down(a4, 32, 64); a5 += __shfl_down(a5, 32, 64);
    a6 += __shfl_down(a6, 32, 64); a7 += __shfl_down(a7, 32, 64);
    wsum += __shfl_down(wsum, 32, 64);
    a0 += __shfl_down(a0, 16, 64); a1 += __shfl_down(a1, 16, 64);
    a2 += __shfl_down(a2, 16, 64); a3 += __shfl_down(a3, 16, 64);
    a4 += __shfl_down(a4, 16, 64); a5 += __shfl_down(a5, 16, 64);
    a6 += __shfl_down(a6, 16, 64); a7 += __shfl_down(a7, 16, 64);
    wsum += __shfl_down(wsum, 16, 64);
    a0 += __shfl_down(a0, 8, 64); a1 += __shfl_down(a1, 8, 64);
    a2 += __shfl_down(a2, 8, 64); a3 += __shfl_down(a3, 8, 64);
    a4 += __shfl_down(a4, 8, 64); a5 += __shfl_down(a5, 8, 64);
    a6 += __shfl_down(a6, 8, 64); a7 += __shfl_down(a7, 8, 64);
    wsum += __shfl_down(wsum, 8, 64);
    a0 += __shfl_down(a0, 4, 64); a1 += __shfl_down(a1, 4, 64);
    a2 += __shfl_down(a2, 4, 64); a3 += __shfl_down(a3, 4, 64);
    a4 += __shfl_down(a4, 4, 64); a5 += __shfl_down(a5, 4, 64);
    a6 += __shfl_down(a6, 4, 64); a7 += __shfl_down(a7, 4, 64);
    wsum += __shfl_down(wsum, 4, 64);

    // ---- fused +b2 and log_softmax over the 4-lane group ----
    const float inv = 1.f / (wsum + 1e-16f);
    const float4 b2a = *(const float4*)&b2[c * 8];
    const float4 b2b = *(const float4*)&b2[c * 8 + 4];
    const float v0 = a0 * inv + b2a.x, v1 = a1 * inv + b2a.y;
    const float v2 = a2 * inv + b2a.z, v3 = a3 * inv + b2a.w;
    const float v4 = a4 * inv + b2b.x, v5 = a5 * inv + b2b.y;
    const float v6 = a6 * inv + b2b.z, v7 = a7 * inv + b2b.w;
    float mx = fmaxf(fmaxf(fmaxf(v0, v1), fmaxf(v2, v3)),
                     fmaxf(fmaxf(v4, v5), fmaxf(v6, v7)));
    mx = fmaxf(mx, __shfl_xor(mx, 1, 64));
    mx = fmaxf(mx, __shfl_xor(mx, 2, 64));
    float s = __expf(v0 - mx) + __expf(v1 - mx) + __expf(v2 - mx) + __expf(v3 - mx)
            + __expf(v4 - mx) + __expf(v5 - mx) + __expf(v6 - mx) + __expf(v7 - mx);
    s += __shfl_xor(s, 1, 64);
    s += __shfl_xor(s, 2, 64);
    const float lse = mx + logf(s);
    if (l < 4) {
        float* op = &out[(size_t)n * NCLASS + c * 8];
        *(float4*)&op[0] = make_float4(v0 - lse, v1 - lse, v2 - lse, v3 - lse);
        *(float4*)&op[4] = make_float4(v4 - lse, v5 - lse, v6 - lse, v7 - lse);
    }
}

extern "C" void kernel_launch(void* const* d_in, const int* in_sizes, int n_in,
                              void* d_out, int out_size, void* d_ws, size_t ws_size,
                              hipStream_t stream) {
    const float* x      = (const float*)d_in[0];
    const int*   ei     = (const int*)d_in[1];
    const float* W1     = (const float*)d_in[2];
    const float* a_src1 = (const float*)d_in[3];
    const float* a_dst1 = (const float*)d_in[4];
    const float* b1     = (const float*)d_in[5];
    const float* W2     = (const float*)d_in[6];
    const float* a_src2 = (const float*)d_in[7];
    const float* a_dst2 = (const float*)d_in[8];
    const float* b2     = (const float*)d_in[9];
    float* out = (float*)d_out;
    float* ws  = (float*)d_ws;

    ushort* h1u     = (ushort*)(ws + OFF_H1);
    unsigned* h1b   = (unsigned*)(ws + OFF_H1);
    unsigned* h2b   = (unsigned*)(ws + OFF_H2);
    float* als1     = ws + OFF_ALS1;
    float* ald1     = ws + OFF_ALD1;
    float* als2     = ws + OFF_ALS2;
    float* ald2     = ws + OFF_ALD2;
    int*   bcur     = (int*)(ws + OFF_BCUR);
    int*   row_ptr  = (int*)(ws + OFF_ROWP);
    int*   cnt      = (int*)(ws + OFF_CNT);
    int*   bin      = (int*)(ws + OFF_BIN);
    int*   csr      = (int*)(ws + OFF_CSR);

    hipMemsetAsync(bcur, 0, NBUCK * sizeof(int), stream);

    bin_kernel<<<(E_TOT + BIN_EPB - 1) / BIN_EPB, 256, 0, stream>>>(ei, bcur, bin);
    gemm1_bsort_kernel<<<NBUCK + GEMM1_NB, 256, 0, stream>>>(x, W1, a_src1, a_dst1,
                                                             h1u, als1, ald1,
                                                             bcur, bin, csr, row_ptr, cnt);
    gather1_kernel<<<N_NODES / 4, 256, 0, stream>>>(row_ptr, cnt, csr, h1b, als1, ald1,
                                                    b1, W2, a_src2, a_dst2, h2b, als2, ald2);
    gather2_kernel<<<N_NODES / 4, 256, 0, stream>>>(row_ptr, cnt, csr, h2b, als2, ald2, b2, out);
}

// Round 14
// 329.179 us; speedup vs baseline: 1.0489x; 1.0489x over previous
//
#include <hip/hip_runtime.h>
#include <math.h>

#define N_NODES 100000
#define NFEAT 256
#define D1 64          // HEADS*NHID
#define HEADS 8
#define NHID 8
#define NCLASS 32
#define NUM_EDGES 1600000
#define E_TOT 1700000  // + self loops
#define NEG_SLOPE 0.2f

// dst-bucketing: 256 nodes per bucket; CSR stored bucket-strided (no compaction)
#define BSHIFT 8
#define NBUCK 391            // ceil(100000/256)
#define BCAP 5120            // mean edges/bucket 4352, std ~66; +11.6 sigma headroom
#define BIN_EPB 4096
#define BIN_EPT 16
#define GEMM1_NB 1563        // ceil(100000/64)

// R1STRIDE/R2STRIDE: interleaved per-node records (word units)
//   layer1: [als1(8 floats) | h1(32 uints, 64 bf16)]  stride 40 (160B)
//   layer2: [als2(1 float) pad(3) | h2(16 uints)]     stride 20 (80B)
#define R1S 40
#define R2S 20

// LESSON (r4): wave-per-node x 25k waves >> block-per-bucket (TLP hides gather latency).
// LESSON (r9/r14): gather MLP (8 edge slots x uint4 + 2-deep pipeline) 76->63us.
// LESSON (r10-r13): gemm1 pipelining only sticks with __syncthreads between issue & use.
// LESSON (r16-r21): fused layer2/logsoftmax into gathers; fast_elu; barrier-FREE
// wave-local epilogue (zbuf per-wave + wave_barrier): 96->74us.
// LESSON (r22): role-split block fusion {bsort | gemm1} hides bsort under gemm1 (-8us).
// LESSON (r24): sentinel-padding REGRESSED (+16us): mean deg 17 padded to mult-16 =
// +50% edge work; guard removal saved less. REVERTED to guarded loops.
// NEW (r24): interleaved records [als|h] -> ONE record-base address per edge instead of
// two independent mul+add+64b chains; als shares cache lines with h. Attacks the 82%
// VALU bound via addressing, not math.

// ---- workspace layout (float offsets) ----
#define OFF_H1R   0            // 100000*40 = 4,000,000 words
#define OFF_H2R   4000000      // 100000*20 = 2,000,000 words
#define OFF_ALD1  6400000      // 800,000
#define OFF_ALD2  7300000      // 100,000
#define OFF_BCUR  7500000      // 1024
#define OFF_ROWP  7501024      // 100,000
#define OFF_CNT   7601024      // 100,000
#define OFF_BIN   7701024      // 391*5120
#define OFF_CSR   9702944      // 391*5120 (ends ~11.7M f = 47MB)

typedef __attribute__((ext_vector_type(8))) short bf16x8;
typedef __attribute__((ext_vector_type(4))) float f32x4;

__device__ __forceinline__ float lrelu(float x) { return x >= 0.f ? x : NEG_SLOPE * x; }
__device__ __forceinline__ float fast_elu(float x) { return x > 0.f ? x : __expf(x) - 1.f; }

__device__ __forceinline__ unsigned f32_to_bf16_rne(float f) {
    unsigned u = __float_as_uint(f);
    return (u + 0x7fffu + ((u >> 16) & 1u)) >> 16;
}
__device__ __forceinline__ unsigned pack_bf16x2(float lo, float hi) {
    return f32_to_bf16_rne(lo) | (f32_to_bf16_rne(hi) << 16);
}
__device__ __forceinline__ float2 unpack_bf16x2(unsigned v) {
    return make_float2(__uint_as_float(v << 16), __uint_as_float(v & 0xffff0000u));
}

__device__ __forceinline__ void edge_src_dst(const int* __restrict__ ei, int e, int& src, int& dst) {
    if (e < NUM_EDGES) { src = ei[e]; dst = ei[NUM_EDGES + e]; }
    else { src = e - NUM_EDGES; dst = e - NUM_EDGES; }
}

// ---------------- K2: bin edges by dst bucket (LDS hist + chunk reservation) ----------------
// packed entry: (dst&255)<<20 | src   (src < 2^17)
__global__ __launch_bounds__(256) void bin_kernel(const int* __restrict__ ei,
                                                  int* __restrict__ bcur,
                                                  int* __restrict__ bin) {
    __shared__ int lcnt[NBUCK];
    __shared__ int lbase[NBUCK];
    const int tid = threadIdx.x;
    for (int b = tid; b < NBUCK; b += 256) lcnt[b] = 0;
    __syncthreads();
    const int e0 = blockIdx.x * BIN_EPB;
    int pk[BIN_EPT], bk[BIN_EPT], loff[BIN_EPT];
#pragma unroll
    for (int i = 0; i < BIN_EPT; i++) {
        const int e = e0 + i * 256 + tid;
        if (e < E_TOT) {
            int src, dst; edge_src_dst(ei, e, src, dst);
            bk[i] = dst >> BSHIFT;
            pk[i] = ((dst & 255) << 20) | src;
            loff[i] = atomicAdd(&lcnt[bk[i]], 1);
        } else bk[i] = -1;
    }
    __syncthreads();
    for (int b = tid; b < NBUCK; b += 256) {
        const int c = lcnt[b];
        lbase[b] = c ? atomicAdd(&bcur[b], c) : 0;
    }
    __syncthreads();
#pragma unroll
    for (int i = 0; i < BIN_EPT; i++) {
        if (bk[i] >= 0)
            bin[(size_t)bk[i] * BCAP + lbase[bk[i]] + loff[i]] = pk[i];
    }
}

// ---------------- K1+K3 merged: role-split blocks -------------------------------------
// blocks [0, NBUCK): bsort (LDS counting sort); blocks [NBUCK, NBUCK+1563): gemm1.
// LDS: 23552-byte union (bsort footprint; gemm1 uses 10240 of it).
__global__ __launch_bounds__(256) void gemm1_bsort_kernel(const float* __restrict__ x,
                                                          const float* __restrict__ W1,
                                                          const float* __restrict__ a_src,
                                                          const float* __restrict__ a_dst,
                                                          unsigned* __restrict__ h1r,
                                                          float* __restrict__ ald,
                                                          const int* __restrict__ bcur,
                                                          const int* __restrict__ bin,
                                                          int* __restrict__ csr,
                                                          int* __restrict__ row_ptr,
                                                          int* __restrict__ cnt) {
    __shared__ __align__(16) unsigned char smem[23552];
    const int tid = threadIdx.x;

    if (blockIdx.x < NBUCK) {
        // ---- bsort role (r12-verified) ----
        int* hcnt = (int*)smem;          // 256
        int* hpre = hcnt + 256;          // 256
        int* curp = hpre + 256;          // 256
        int* ssrc = curp + 256;          // BCAP (20 KB)
        const int bkt = blockIdx.x;
        const int cntb = bcur[bkt];
        const int base = bkt * BCAP;
        hcnt[tid] = 0;
        __syncthreads();
        for (int i = tid; i < cntb; i += 256)
            atomicAdd(&hcnt[bin[base + i] >> 20], 1);
        __syncthreads();
        const int myc = hcnt[tid];
        hpre[tid] = myc;
        __syncthreads();
        for (int off = 1; off < 256; off <<= 1) {
            const int t = (tid >= off) ? hpre[tid - off] : 0;
            __syncthreads();
            hpre[tid] += t;
            __syncthreads();
        }
        const int exc = hpre[tid] - myc;
        curp[tid] = exc;
        __syncthreads();
        for (int i = tid; i < cntb; i += 256) {
            const int v = bin[base + i];
            const int pos = atomicAdd(&curp[v >> 20], 1);
            ssrc[pos] = v & 0xFFFFF;
        }
        __syncthreads();
        for (int i = tid; i < cntb; i += 256) csr[base + i] = ssrc[i];
        const int n = (bkt << BSHIFT) + tid;
        if (n < N_NODES) { row_ptr[n] = base + exc; cnt[n] = myc; }
        return;
    }

    // ---- gemm1 role ----
    unsigned* xbf = (unsigned*)smem;     // [2][64*20] uints (10240 B)
    float* h1f = (float*)h1r;
    ushort* h1s = (ushort*)h1r;
    const int wv = tid >> 6;             // wave = col-tile
    const int l = tid & 63;
    const int lm = l & 15;
    const int quad = l >> 4;
    const int r0 = (blockIdx.x - NBUCK) * 64;

    // B-fragments: this wave's 16-col slice of W1, all 8 K-chunks, in registers (32 VGPRs)
    bf16x8 bfrag[8];
#pragma unroll
    for (int kb = 0; kb < 8; kb++)
#pragma unroll
        for (int j = 0; j < 8; j++) {
            const int k = kb * 32 + quad * 8 + j;
            bfrag[kb][j] = (short)f32_to_bf16_rne(W1[k * D1 + wv * 16 + lm]);
        }

    f32x4 acc[4];
#pragma unroll
    for (int s = 0; s < 4; s++) acc[s] = (f32x4)(0.f);

    const int sr = tid >> 2;            // staging: row 0..63
    const int sk = (tid & 3) * 8;       // k-offset within 32-chunk
    const bool rok = (r0 + sr) < N_NODES;
    const float* xrow = &x[(size_t)(r0 + sr) * NFEAT];
    const int swrd = sr * 20 + (tid & 3) * 4;   // LDS write word offset

    // prologue: load + pack + write chunk 0 into buf 0
    {
        uint4 pv = make_uint4(0, 0, 0, 0);
        if (rok) {
            const float4 va = *(const float4*)&xrow[sk];
            const float4 vb = *(const float4*)&xrow[sk + 4];
            pv.x = pack_bf16x2(va.x, va.y);
            pv.y = pack_bf16x2(va.z, va.w);
            pv.z = pack_bf16x2(vb.x, vb.y);
            pv.w = pack_bf16x2(vb.z, vb.w);
        }
        *(uint4*)&xbf[swrd] = pv;
    }
    __syncthreads();

#pragma unroll
    for (int kb = 0; kb < 8; kb++) {
        const int cur = kb & 1;
        const int nxt = cur ^ 1;
        float4 na = make_float4(0.f, 0.f, 0.f, 0.f);
        float4 nb = make_float4(0.f, 0.f, 0.f, 0.f);
        if (kb < 7 && rok) {
            na = *(const float4*)&xrow[(kb + 1) * 32 + sk];
            nb = *(const float4*)&xrow[(kb + 1) * 32 + sk + 4];
        }
#pragma unroll
        for (int s = 0; s < 4; s++) {
            const uint4 u = *(const uint4*)&xbf[cur * 1280 + (s * 16 + lm) * 20 + quad * 4];
            const bf16x8 af = *(const bf16x8*)&u;
            acc[s] = __builtin_amdgcn_mfma_f32_16x16x32_bf16(af, bfrag[kb], acc[s], 0, 0, 0);
        }
        if (kb < 7) {
            uint4 pv;
            pv.x = pack_bf16x2(na.x, na.y);
            pv.y = pack_bf16x2(na.z, na.w);
            pv.z = pack_bf16x2(nb.x, nb.y);
            pv.w = pack_bf16x2(nb.z, nb.w);
            *(uint4*)&xbf[nxt * 1280 + swrd] = pv;
            __syncthreads();
        }
    }

    // epilogue: h1 bf16 + als1 into the interleaved record; ald separate
    const int head = wv * 2 + (lm >> 3);
    const int jc = l & 7;
    const float asl = a_src[head * NHID + jc];
    const float adl = a_dst[head * NHID + jc];
    const int col = wv * 16 + lm;
#pragma unroll
    for (int s = 0; s < 4; s++) {
#pragma unroll
        for (int r = 0; r < 4; r++) {
            const int row = r0 + s * 16 + quad * 4 + r;
            const float v = acc[s][r];
            float ps = v * asl, pd = v * adl;
            ps += __shfl_xor(ps, 1, 64); pd += __shfl_xor(pd, 1, 64);
            ps += __shfl_xor(ps, 2, 64); pd += __shfl_xor(pd, 2, 64);
            ps += __shfl_xor(ps, 4, 64); pd += __shfl_xor(pd, 4, 64);
            if (row < N_NODES) {
                // record word row*R1S: [als(8f) | h1(32 u)]; h1 ushort idx = row*80+16+col
                h1s[(size_t)row * (R1S * 2) + 16 + col] = (ushort)f32_to_bf16_rne(v);
                if (jc == 0) { h1f[(size_t)row * R1S + head] = ps; ald[row * HEADS + head] = pd; }
            }
        }
    }
}

// ---------------- K4: gather layer 1 + FUSED layer2 (record layout, barrier-free) --------
// Wave/node, 8 lanes x uint4 (head octet), 8 edge slots, 2-deep value pipeline.
// Per edge: ONE record base (s*R1S); als at +h, h1 quad at +8+h*4 (same chain).
__global__ __launch_bounds__(256) void gather1_kernel(const int* __restrict__ row_ptr,
                                                      const int* __restrict__ cnt,
                                                      const int* __restrict__ csr_src,
                                                      const unsigned* __restrict__ h1r,
                                                      const float* __restrict__ ald,
                                                      const float* __restrict__ b1,
                                                      const float* __restrict__ W2,
                                                      const float* __restrict__ a_src2,
                                                      const float* __restrict__ a_dst2,
                                                      unsigned* __restrict__ h2r,
                                                      float* __restrict__ ald2) {
    __shared__ float zbuf[4][64];                // per-wave z row (1 KB)
    const float* h1f = (const float*)h1r;
    float* h2f = (float*)h2r;
    const int tid = threadIdx.x;
    const int wv = tid >> 6;
    const int n = blockIdx.x * 4 + wv;           // grid == N_NODES/4 exactly
    const int l = tid & 63;
    const int q = l >> 3;                        // edge slot 0..7
    const int h = l & 7;                         // head = channel octet 8h..8h+7
    const unsigned hoff = 8u + h * 4u;           // h1 quad offset within record
    const int start = row_ptr[n];
    const int deg = cnt[n];
    const float aldn = ald[n * HEADS + h];
    float a0 = 0.f, a1 = 0.f, a2 = 0.f, a3 = 0.f;
    float a4 = 0.f, a5 = 0.f, a6 = 0.f, a7 = 0.f, wsum = 0.f;

    int i = q;
    float e0 = 0.f, e1 = 0.f;
    uint4 u0 = make_uint4(0u, 0u, 0u, 0u);
    uint4 u1 = make_uint4(0u, 0u, 0u, 0u);
    int s2 = 0;
    if (i < deg) {
        const unsigned rec = (unsigned)csr_src[start + i] * R1S;
        e0 = h1f[rec + h];
        u0 = *(const uint4*)&h1r[rec + hoff];
    }
    if (i + 8 < deg) {
        const unsigned rec = (unsigned)csr_src[start + i + 8] * R1S;
        e1 = h1f[rec + h];
        u1 = *(const uint4*)&h1r[rec + hoff];
    }
    if (i + 16 < deg) s2 = csr_src[start + i + 16];

#pragma unroll 2
    for (; i < deg; i += 8) {
        int s3 = 0;
        if (i + 24 < deg) s3 = csr_src[start + i + 24];
        float e2 = 0.f;
        uint4 u2 = make_uint4(0u, 0u, 0u, 0u);
        if (i + 16 < deg) {
            const unsigned rec = (unsigned)s2 * R1S;
            e2 = h1f[rec + h];
            u2 = *(const uint4*)&h1r[rec + hoff];
        }
        const float w = __expf(lrelu(e0 + aldn));
        const float2 p0 = unpack_bf16x2(u0.x);
        const float2 p1 = unpack_bf16x2(u0.y);
        const float2 p2 = unpack_bf16x2(u0.z);
        const float2 p3 = unpack_bf16x2(u0.w);
        a0 = fmaf(p0.x, w, a0); a1 = fmaf(p0.y, w, a1);
        a2 = fmaf(p1.x, w, a2); a3 = fmaf(p1.y, w, a3);
        a4 = fmaf(p2.x, w, a4); a5 = fmaf(p2.y, w, a5);
        a6 = fmaf(p3.x, w, a6); a7 = fmaf(p3.y, w, a7);
        wsum += w;
        e0 = e1; u0 = u1; e1 = e2; u1 = u2; s2 = s3;
    }

    // reduce across the 8 slots (8-lane groups)
    a0 += __shfl_down(a0, 32, 64); a1 += __shfl_down(a1, 32, 64);
    a2 += __shfl_down(a2, 32, 64); a3 += __shfl_down(a3, 32, 64);
    a4 += __shfl_down(a4, 32, 64); a5 += __shfl_down(a5, 32, 64);
    a6 += __shfl_down(a6, 32, 64); a7 += __shfl_down(a7, 32, 64);
    wsum += __shfl_down(wsum, 32, 64);
    a0 += __shfl_down(a0, 16, 64); a1 += __shfl_down(a1, 16, 64);
    a2 += __shfl_down(a2, 16, 64); a3 += __shfl_down(a3, 16, 64);
    a4 += __shfl_down(a4, 16, 64); a5 += __shfl_down(a5, 16, 64);
    a6 += __shfl_down(a6, 16, 64); a7 += __shfl_down(a7, 16, 64);
    wsum += __shfl_down(wsum, 16, 64);
    a0 += __shfl_down(a0, 8, 64); a1 += __shfl_down(a1, 8, 64);
    a2 += __shfl_down(a2, 8, 64); a3 += __shfl_down(a3, 8, 64);
    a4 += __shfl_down(a4, 8, 64); a5 += __shfl_down(a5, 8, 64);
    a6 += __shfl_down(a6, 8, 64); a7 += __shfl_down(a7, 8, 64);
    wsum += __shfl_down(wsum, 8, 64);

    // ---- fused layer2 (wave-local; fast_elu = single v_exp, r17 lesson) ----
    if (l < 8) {                                  // lane l holds channels 8l..8l+7
        const float inv = 1.f / (wsum + 1e-16f);
        const float4 b1a = *(const float4*)&b1[l * 8];
        const float4 b1b = *(const float4*)&b1[l * 8 + 4];
        const float z0 = fast_elu(a0 * inv + b1a.x);
        const float z1 = fast_elu(a1 * inv + b1a.y);
        const float z2 = fast_elu(a2 * inv + b1a.z);
        const float z3 = fast_elu(a3 * inv + b1a.w);
        const float z4 = fast_elu(a4 * inv + b1b.x);
        const float z5 = fast_elu(a5 * inv + b1b.y);
        const float z6 = fast_elu(a6 * inv + b1b.z);
        const float z7 = fast_elu(a7 * inv + b1b.w);
        *(float4*)&zbuf[wv][l * 8]     = make_float4(z0, z1, z2, z3);
        *(float4*)&zbuf[wv][l * 8 + 4] = make_float4(z4, z5, z6, z7);
    }
    __builtin_amdgcn_wave_barrier();             // pin DS write<->read program order
    asm volatile("" ::: "memory");               // forbid compiler value-forwarding

    // y[c] = sum_k z[k] * W2[k][c]; W2 direct from global (L1/L2-hot, r9-verified),
    // 4 partial accumulators to break the serial fmaf chain.
    const int c = l & 31;                         // output class
    const int kh = l >> 5;                        // k-half
    float y0 = 0.f, y1 = 0.f, y2 = 0.f, y3 = 0.f;
    const float* wbase = &W2[(kh * 32) * NCLASS + c];
#pragma unroll
    for (int j4 = 0; j4 < 2; j4++) {
        const int k0 = j4 * 16;
        const float4 za = *(const float4*)&zbuf[wv][kh * 32 + k0];
        const float4 zb = *(const float4*)&zbuf[wv][kh * 32 + k0 + 4];
        const float4 zc = *(const float4*)&zbuf[wv][kh * 32 + k0 + 8];
        const float4 zd = *(const float4*)&zbuf[wv][kh * 32 + k0 + 12];
        y0 = fmaf(za.x, wbase[(k0 + 0) * NCLASS], y0);
        y1 = fmaf(za.y, wbase[(k0 + 1) * NCLASS], y1);
        y2 = fmaf(za.z, wbase[(k0 + 2) * NCLASS], y2);
        y3 = fmaf(za.w, wbase[(k0 + 3) * NCLASS], y3);
        y0 = fmaf(zb.x, wbase[(k0 + 4) * NCLASS], y0);
        y1 = fmaf(zb.y, wbase[(k0 + 5) * NCLASS], y1);
        y2 = fmaf(zb.z, wbase[(k0 + 6) * NCLASS], y2);
        y3 = fmaf(zb.w, wbase[(k0 + 7) * NCLASS], y3);
        y0 = fmaf(zc.x, wbase[(k0 + 8) * NCLASS], y0);
        y1 = fmaf(zc.y, wbase[(k0 + 9) * NCLASS], y1);
        y2 = fmaf(zc.z, wbase[(k0 + 10) * NCLASS], y2);
        y3 = fmaf(zc.w, wbase[(k0 + 11) * NCLASS], y3);
        y0 = fmaf(zd.x, wbase[(k0 + 12) * NCLASS], y0);
        y1 = fmaf(zd.y, wbase[(k0 + 13) * NCLASS], y1);
        y2 = fmaf(zd.z, wbase[(k0 + 14) * NCLASS], y2);
        y3 = fmaf(zd.w, wbase[(k0 + 15) * NCLASS], y3);
    }
    float y = (y0 + y1) + (y2 + y3);
    y += __shfl_xor(y, 32, 64);                   // full y[c] on all lanes

    // layer-2 logit dots: lower half reduces y*a_src2, upper half y*a_dst2
    float part = y * ((l < 32) ? a_src2[c] : a_dst2[c]);
    part += __shfl_xor(part, 1, 64);
    part += __shfl_xor(part, 2, 64);
    part += __shfl_xor(part, 4, 64);
    part += __shfl_xor(part, 8, 64);
    part += __shfl_xor(part, 16, 64);
    const float tdv = __shfl(part, 32, 64);       // td (upper-half sum)
    if (l == 0) { h2f[(size_t)n * R2S] = part; ald2[n] = tdv; }

    // pack h2 bf16 into record words n*R2S+4 .. +19
    const unsigned pw = pack_bf16x2(y, __shfl_down(y, 1, 64));
    if (l < 32 && (l & 1) == 0) h2r[(size_t)n * R2S + 4 + (l >> 1)] = pw;
}

// ---------------- K5: gather layer 2 + FUSED log_softmax (record layout) ----------------
// Wave/node, 4 lanes x uint4 (8ch), 16 edge slots, 2-deep pipeline.
__global__ __launch_bounds__(256) void gather2_kernel(const int* __restrict__ row_ptr,
                                                      const int* __restrict__ cnt,
                                                      const int* __restrict__ csr_src,
                                                      const unsigned* __restrict__ h2r,
                                                      const float* __restrict__ ald2,
                                                      const float* __restrict__ b2,
                                                      float* __restrict__ out) {
    const float* h2f = (const float*)h2r;
    const int tid = threadIdx.x;
    const int n = blockIdx.x * 4 + (tid >> 6);   // grid == N_NODES/4 exactly
    const int l = tid & 63;
    const int q = l >> 2;                        // edge slot 0..15
    const int c = l & 3;                         // channel octet: ch 8c..8c+7
    const unsigned coff = 4u + c * 4u;           // h2 quad offset within record
    const int start = row_ptr[n];
    const int deg = cnt[n];
    const float aldn = ald2[n];
    float a0 = 0.f, a1 = 0.f, a2 = 0.f, a3 = 0.f;
    float a4 = 0.f, a5 = 0.f, a6 = 0.f, a7 = 0.f, wsum = 0.f;

    int i = q;
    float e0 = 0.f, e1 = 0.f;
    uint4 u0 = make_uint4(0u, 0u, 0u, 0u);
    uint4 u1 = make_uint4(0u, 0u, 0u, 0u);
    int s2 = 0;
    if (i < deg) {
        const unsigned rec = (unsigned)csr_src[start + i] * R2S;
        e0 = h2f[rec];
        u0 = *(const uint4*)&h2r[rec + coff];
    }
    if (i + 16 < deg) {
        const unsigned rec = (unsigned)csr_src[start + i + 16] * R2S;
        e1 = h2f[rec];
        u1 = *(const uint4*)&h2r[rec + coff];
    }
    if (i + 32 < deg) s2 = csr_src[start + i + 32];

#pragma unroll 2
    for (; i < deg; i += 16) {
        int s3 = 0;
        if (i + 48 < deg) s3 = csr_src[start + i + 48];
        float e2 = 0.f;
        uint4 u2 = make_uint4(0u, 0u, 0u, 0u);
        if (i + 32 < deg) {
            const unsigned rec = (unsigned)s2 * R2S;
            e2 = h2f[rec];
            u2 = *(const uint4*)&h2r[rec + coff];
        }
        const float w = __expf(lrelu(e0 + aldn));
        const float2 p0 = unpack_bf16x2(u0.x);
        const float2 p1 = unpack_bf16x2(u0.y);
        const float2 p2 = unpack_bf16x2(u0.z);
        const float2 p3 = unpack_bf16x2(u0.w);
        a0 = fmaf(p0.x, w, a0); a1 = fmaf(p0.y, w, a1);
        a2 = fmaf(p1.x, w, a2); a3 = fmaf(p1.y, w, a3);
        a4 = fmaf(p2.x, w, a4); a5 = fmaf(p2.y, w, a5);
        a6 = fmaf(p3.x, w, a6); a7 = fmaf(p3.y, w, a7);
        wsum += w;
        e0 = e1; u0 = u1; e1 = e2; u1 = u2; s2 = s3;
    }

    // reduce across the 16 slots (4-lane groups)
    a0 += __shfl_down(a0, 32, 64); a1 += __shfl_down(a1, 32, 64);
    a2 += __shfl_down(a2, 32, 64); a3 += __shfl_down(a3, 32, 64);
    a4 += __shfl_down(a4, 32, 64); a5 += __shfl_down(a5, 32, 64);
    a6 += __shfl_down(a6, 32, 64); a7 += __shfl_down(a7, 32, 64);
    wsum += __shfl_down(wsum, 32, 64);
    a0 += __shfl_down(a0, 16, 64); a1 += __shfl_down(a1, 16, 64);
    a2 += __shfl_down(a2, 16, 64); a3 += __shfl_down(a3, 16, 64);
    a4 += __shfl_down(a4, 16, 64); a5 += __shfl_down(a5, 16, 64);
    a6 += __shfl_down(a6, 16, 64); a7 += __shfl_down(a7, 16, 64);
    wsum += __shfl_down(wsum, 16, 64);
    a0 += __shfl_down(a0, 8, 64); a1 += __shfl_down(a1, 8, 64);
    a2 += __shfl_down(a2, 8, 64); a3 += __shfl_down(a3, 8, 64);
    a4 += __shfl_down(a4, 8, 64); a5 += __shfl_down(a5, 8, 64);
    a6 += __shfl_down(a6, 8, 64); a7 += __shfl_down(a7, 8, 64);
    wsum += __shfl_down(wsum, 8, 64);
    a0 += __shfl_down(a0, 4, 64); a1 += __shfl_down(a1, 4, 64);
    a2 += __shfl_down(a2, 4, 64); a3 += __shfl_down(a3, 4, 64);
    a4 += __shfl_down(a4, 4, 64); a5 += __shfl_down(a5, 4, 64);
    a6 += __shfl_down(a6, 4, 64); a7 += __shfl_down(a7, 4, 64);
    wsum += __shfl_down(wsum, 4, 64);

    // ---- fused +b2 and log_softmax over the 4-lane group ----
    const float inv = 1.f / (wsum + 1e-16f);
    const float4 b2a = *(const float4*)&b2[c * 8];
    const float4 b2b = *(const float4*)&b2[c * 8 + 4];
    const float v0 = a0 * inv + b2a.x, v1 = a1 * inv + b2a.y;
    const float v2 = a2 * inv + b2a.z, v3 = a3 * inv + b2a.w;
    const float v4 = a4 * inv + b2b.x, v5 = a5 * inv + b2b.y;
    const float v6 = a6 * inv + b2b.z, v7 = a7 * inv + b2b.w;
    float mx = fmaxf(fmaxf(fmaxf(v0, v1), fmaxf(v2, v3)),
                     fmaxf(fmaxf(v4, v5), fmaxf(v6, v7)));
    mx = fmaxf(mx, __shfl_xor(mx, 1, 64));
    mx = fmaxf(mx, __shfl_xor(mx, 2, 64));
    float s = __expf(v0 - mx) + __expf(v1 - mx) + __expf(v2 - mx) + __expf(v3 - mx)
            + __expf(v4 - mx) + __expf(v5 - mx) + __expf(v6 - mx) + __expf(v7 - mx);
    s += __shfl_xor(s, 1, 64);
    s += __shfl_xor(s, 2, 64);
    const float lse = mx + logf(s);
    if (l < 4) {
        float* op = &out[(size_t)n * NCLASS + c * 8];
        *(float4*)&op[0] = make_float4(v0 - lse, v1 - lse, v2 - lse, v3 - lse);
        *(float4*)&op[4] = make_float4(v4 - lse, v5 - lse, v6 - lse, v7 - lse);
    }
}

extern "C" void kernel_launch(void* const* d_in, const int* in_sizes, int n_in,
                              void* d_out, int out_size, void* d_ws, size_t ws_size,
                              hipStream_t stream) {
    const float* x      = (const float*)d_in[0];
    const int*   ei     = (const int*)d_in[1];
    const float* W1     = (const float*)d_in[2];
    const float* a_src1 = (const float*)d_in[3];
    const float* a_dst1 = (const float*)d_in[4];
    const float* b1     = (const float*)d_in[5];
    const float* W2     = (const float*)d_in[6];
    const float* a_src2 = (const float*)d_in[7];
    const float* a_dst2 = (const float*)d_in[8];
    const float* b2     = (const float*)d_in[9];
    float* out = (float*)d_out;
    float* ws  = (float*)d_ws;

    unsigned* h1r   = (unsigned*)(ws + OFF_H1R);
    unsigned* h2r   = (unsigned*)(ws + OFF_H2R);
    float* ald1     = ws + OFF_ALD1;
    float* ald2     = ws + OFF_ALD2;
    int*   bcur     = (int*)(ws + OFF_BCUR);
    int*   row_ptr  = (int*)(ws + OFF_ROWP);
    int*   cnt      = (int*)(ws + OFF_CNT);
    int*   bin      = (int*)(ws + OFF_BIN);
    int*   csr      = (int*)(ws + OFF_CSR);

    hipMemsetAsync(bcur, 0, NBUCK * sizeof(int), stream);

    bin_kernel<<<(E_TOT + BIN_EPB - 1) / BIN_EPB, 256, 0, stream>>>(ei, bcur, bin);
    gemm1_bsort_kernel<<<NBUCK + GEMM1_NB, 256, 0, stream>>>(x, W1, a_src1, a_dst1,
                                                             h1r, ald1,
                                                             bcur, bin, csr, row_ptr, cnt);
    gather1_kernel<<<N_NODES / 4, 256, 0, stream>>>(row_ptr, cnt, csr, h1r, ald1,
                                                    b1, W2, a_src2, a_dst2, h2r, ald2);
    gather2_kernel<<<N_NODES / 4, 256, 0, stream>>>(row_ptr, cnt, csr, h2r, ald2, b2, out);
}